// Round 13
// baseline (13.311 us; speedup 1.0000x reference)
//
#include <hip/hip_runtime.h>

// Problem constants (match reference)
#define B_ 16
#define N_ 8192
#define U_ 64        // INPUT_DIM
#define W_ 128       // LATENT_DIM
#define BLOCKS_PER_B 32
#define ROWS_PER_BLOCK (N_ / BLOCKS_PER_B)   // 256 = blockDim
#define GRID_ (B_ * BLOCKS_PER_B)            // 512 blocks = 2 blocks/CU exactly

typedef float f32x4 __attribute__((ext_vector_type(4)));

// ws layout: [GRID_][256] block-partial sums (512 KiB).
//   slot = u*4 + j; j==0 -> sum feat_u, j=1..3 -> sum feat_u * nhat_{j-1}
// out layout: [B,512]: o<128 scalar path, 128+3w+k vector path
//
// R12 change under test: REMOVED nontemporal loads. R4's counters showed
// FETCH_SIZE ~17.8MB for a 33.5MB input -> the input is partially
// L3-resident across graph replays; nt (no-allocate) loads would defeat
// that reuse and pin the read stream to HBM. Everything else identical
// to R12 (LDS normals, 16-deep static prefetch, __launch_bounds__(256,2)).

__global__ __launch_bounds__(256, 2) void so3_reduce_kernel(
    const float* __restrict__ feat,   // [B,N,64]
    const float* __restrict__ pos,    // [B,N,3]
    float* __restrict__ ws)           // [GRID_][256] partials
{
    const int blk   = blockIdx.x;              // 0..GRID_-1
    const int b     = blk / BLOCKS_PER_B;
    const int chunk = blk % BLOCKS_PER_B;
    const int row0  = chunk * ROWS_PER_BLOCK;
    const int tid   = threadIdx.x;             // 0..255 (4 waves)
    const int grp   = tid & 15;                // feature group: feats 4*grp..4*grp+3
    const int rsub  = tid >> 4;                // 0..15: row within a 16-row group

    // ---- prologue: normalize pos once per row into LDS ----
    __shared__ f32x4 nlds[ROWS_PER_BLOCK];     // 4 KiB
    {
        const float* p = pos + ((size_t)b * N_ + row0 + tid) * 3;
        const float px = p[0], py = p[1], pz = p[2];   // block-coalesced 3 KiB
        const float inv = rsqrtf(px * px + py * py + pz * pz);
        f32x4 v;
        v.x = px * inv; v.y = py * inv; v.z = pz * inv; v.w = 1.0f;
        nlds[tid] = v;
    }
    __syncthreads();

    const f32x4* fbase = (const f32x4*)(feat + (size_t)b * N_ * U_);

    // ---- full prefetch: issue all 16 dwordx4 loads up front (regular,
    //      cache-allocating loads -> L3 reuse across replays) ----
    f32x4 fb[16];
    #pragma unroll
    for (int it = 0; it < 16; ++it) {
        const int nl = it * 16 + rsub;         // local row
        fb[it] = fbase[(size_t)(row0 + nl) * 16 + grp];
    }

    // acc[i][k]: i = feat sub-index (4*grp+i), k = 0..2 -> M[k], k = 3 -> S.
    float acc[4][4] = {{0.f,0.f,0.f,0.f},{0.f,0.f,0.f,0.f},
                       {0.f,0.f,0.f,0.f},{0.f,0.f,0.f,0.f}};

    #pragma unroll
    for (int it = 0; it < 16; ++it) {
        const int nl = it * 16 + rsub;
        const f32x4 f  = fb[it];
        const f32x4 nv = nlds[nl];             // ds_read_b128, 16-way broadcast
        #pragma unroll
        for (int k = 0; k < 4; ++k) {
            const float nk = (k == 0) ? nv.x : (k == 1) ? nv.y
                           : (k == 2) ? nv.z : nv.w;   // nv.w == 1.0 -> sum
            acc[0][k] = fmaf(f.x, nk, acc[0][k]);
            acc[1][k] = fmaf(f.y, nk, acc[1][k]);
            acc[2][k] = fmaf(f.z, nk, acc[2][k]);
            acc[3][k] = fmaf(f.w, nk, acc[3][k]);
        }
    }

    // Block-level combine via LDS (pad 17 breaks the stride-16 bank pattern).
    // lds[tid][i*4+k] = acc[i][k].
    __shared__ float lds[256][17];
    #pragma unroll
    for (int i = 0; i < 4; ++i) {
        lds[tid][i * 4 + 0] = acc[i][0];
        lds[tid][i * 4 + 1] = acc[i][1];
        lds[tid][i * 4 + 2] = acc[i][2];
        lds[tid][i * 4 + 3] = acc[i][3];
    }
    __syncthreads();

    // ws slot contract (unchanged): slot tid = (u = tid>>2, j = tid&3);
    // j==0 -> S (lds k=3), j=1..3 -> M[j-1] (lds k=j-1).
    const int u    = tid >> 2;     // 0..63
    const int j    = tid & 3;
    const int ug   = u >> 2;       // writer feature-group (grp)
    const int sub  = u & 3;        // writer's sub-index i
    const int slot = (j == 0) ? (sub * 4 + 3) : (sub * 4 + (j - 1));
    float s = 0.f;
    #pragma unroll
    for (int src = 0; src < 16; ++src) {
        const int t = (src & 3) * 64 + (src >> 2) * 16 + ug;  // wave*64 + row-in-wave*16 + ug
        s += lds[t][slot];
    }
    ws[(size_t)blk * 256 + tid] = s;   // coalesced 1 KiB store
}

__global__ __launch_bounds__(512) void so3_finalize_kernel(
    const float* __restrict__ ws,   // [GRID_][256] partials
    const float* __restrict__ W0,   // [64,128]
    const float* __restrict__ W1,   // [64,128]
    float* __restrict__ out)        // [B,512]
{
    const int b   = blockIdx.x;
    const int tid = threadIdx.x;    // 0..511

    // Phase 1: cross-block combine, float4-wide (slot group of 4 = one u).
    const int u4   = tid & 63;      // float4 index within a chunk row
    const int cgrp = tid >> 6;      // 0..7: chunk group

    __shared__ float4 smf4[8][64];  // 8 KiB
    __shared__ float  sm[256];

    {
        const float4* base = (const float4*)(ws + (size_t)b * BLOCKS_PER_B * 256);
        float4 a = {0.f, 0.f, 0.f, 0.f};
        #pragma unroll
        for (int c = 0; c < 4; ++c) {
            const float4 v = base[(size_t)(cgrp * 4 + c) * 64 + u4];
            a.x += v.x; a.y += v.y; a.z += v.z; a.w += v.w;
        }
        smf4[cgrp][u4] = a;
    }
    __syncthreads();

    if (tid < 64) {
        float4 t = smf4[0][tid];
        #pragma unroll
        for (int g = 1; g < 8; ++g) {
            const float4 v = smf4[g][tid];
            t.x += v.x; t.y += v.y; t.z += v.z; t.w += v.w;
        }
        ((float4*)sm)[tid] = t;     // sm[u*4 + j]
    }
    __syncthreads();

    // Phase 2: tiny matmul, one output element per thread.
    const float scaleS = 0.125f / (float)N_;                       // PATH_COEFF / N
    const float scaleV = 0.125f * 1.7320508075688772f / (float)N_; // PATH_COEFF*sqrt(3)/N

    const int o = tid;
    float acc = 0.f;
    if (o < 128) {
        #pragma unroll
        for (int uu = 0; uu < 64; ++uu) acc += sm[uu * 4] * W0[uu * 128 + o];
        out[b * 512 + o] = acc * scaleS;
    } else {
        const int idx = o - 128;       // 0..383
        const int w = idx / 3;
        const int k = idx - 3 * w;
        #pragma unroll
        for (int uu = 0; uu < 64; ++uu) acc += sm[uu * 4 + 1 + k] * W1[uu * 128 + w];
        out[b * 512 + 128 + idx] = acc * scaleV;
    }
}

extern "C" void kernel_launch(void* const* d_in, const int* in_sizes, int n_in,
                              void* d_out, int out_size, void* d_ws, size_t ws_size,
                              hipStream_t stream) {
    const float* feat = (const float*)d_in[0];
    const float* pos  = (const float*)d_in[1];
    const float* W0   = (const float*)d_in[2];
    const float* W1   = (const float*)d_in[3];
    float* out = (float*)d_out;
    float* ws  = (float*)d_ws;   // needs GRID_*256*4 = 512 KiB scratch

    so3_reduce_kernel<<<GRID_, 256, 0, stream>>>(feat, pos, ws);
    so3_finalize_kernel<<<B_, 512, 0, stream>>>(ws, W0, W1, out);
}

// Round 16
// 12.667 us; speedup vs baseline: 1.0508x; 1.0508x over previous
//
#include <hip/hip_runtime.h>

// Problem constants (match reference)
#define B_ 16
#define N_ 8192
#define U_ 64        // INPUT_DIM
#define W_ 128       // LATENT_DIM
#define BLOCKS_PER_B 32
#define ROWS_PER_BLOCK (N_ / BLOCKS_PER_B)   // 256 = blockDim
#define NPROD (B_ * BLOCKS_PER_B)            // 512 producer blocks (2/CU)
#define NFIN  B_                             // 16 finalizer blocks (one per batch)
#define GRID_ (NPROD + NFIN)                 // 528
#define SENT 0x5AC3F00Du

typedef float f32x4 __attribute__((ext_vector_type(4)));

// Single-node producer/consumer. R14/R15 failed with BIT-IDENTICAL absmax ->
// deterministic indexing bug, not coherence: the finalizer matmul read the
// producer's internal-lds layout (S at +3) instead of the ws slot contract
// (S at +0, M[k] at +1+k). Fixed here; publish kept as exchange-RMW (executes
// at the device coherence point -- safe against XCD write-back L2s).
// Ledger (real evidence only): R4 grid-sync +107us; R7 threadfence +50us;
// R8 contended-RMW wait +14us. This design: uncontended RMW publish,
// producers never wait on consumers, sole writer per out element.
// ws: [NPROD][256] partials (512 KiB) + NPROD u32 flags (2 KiB).
// ws slot contract: slot = u*4 + j; j==0 -> S, j=1..3 -> M[j-1].
// out layout: [B,512]: o<128 scalar path, 128+3w+k vector path.

__global__ __launch_bounds__(256, 2) void so3_single_kernel(
    const float* __restrict__ feat,   // [B,N,64]
    const float* __restrict__ pos,    // [B,N,3]
    const float* __restrict__ W0,     // [64,128]
    const float* __restrict__ W1,     // [64,128]
    float* __restrict__ out,          // [B,512]
    float* __restrict__ ws)
{
    const int blk = blockIdx.x;
    const int tid = threadIdx.x;      // 0..255 (4 waves)
    unsigned* flags = (unsigned*)(ws + (size_t)NPROD * 256);

    if (blk < NPROD) {
        // ---------------- producer: R12 reduce body ----------------
        const int b     = blk / BLOCKS_PER_B;
        const int chunk = blk % BLOCKS_PER_B;
        const int row0  = chunk * ROWS_PER_BLOCK;
        const int grp   = tid & 15;            // feature group: feats 4*grp..4*grp+3
        const int rsub  = tid >> 4;            // 0..15: row within a 16-row group

        // prologue: normalize pos once per row into LDS
        __shared__ f32x4 nlds[ROWS_PER_BLOCK]; // 4 KiB
        {
            const float* p = pos + ((size_t)b * N_ + row0 + tid) * 3;
            const float px = p[0], py = p[1], pz = p[2];   // coalesced 3 KiB
            const float inv = rsqrtf(px * px + py * py + pz * pz);
            f32x4 v;
            v.x = px * inv; v.y = py * inv; v.z = pz * inv; v.w = 1.0f;
            nlds[tid] = v;
        }
        __syncthreads();

        const f32x4* fbase = (const f32x4*)(feat + (size_t)b * N_ * U_);

        // full prefetch: 16 nontemporal dwordx4 loads up front (static idx)
        f32x4 fb[16];
        #pragma unroll
        for (int it = 0; it < 16; ++it) {
            const int nl = it * 16 + rsub;
            fb[it] = __builtin_nontemporal_load(
                &fbase[(size_t)(row0 + nl) * 16 + grp]);
        }

        // acc[i][k]: i = feat sub-index (4*grp+i), k=0..2 -> M[k], k=3 -> S.
        float acc[4][4] = {{0.f,0.f,0.f,0.f},{0.f,0.f,0.f,0.f},
                           {0.f,0.f,0.f,0.f},{0.f,0.f,0.f,0.f}};

        #pragma unroll
        for (int it = 0; it < 16; ++it) {
            const int nl = it * 16 + rsub;
            const f32x4 f  = fb[it];
            const f32x4 nv = nlds[nl];         // ds_read_b128, 16-way broadcast
            #pragma unroll
            for (int k = 0; k < 4; ++k) {
                const float nk = (k == 0) ? nv.x : (k == 1) ? nv.y
                               : (k == 2) ? nv.z : nv.w;   // nv.w==1.0 -> sum
                acc[0][k] = fmaf(f.x, nk, acc[0][k]);
                acc[1][k] = fmaf(f.y, nk, acc[1][k]);
                acc[2][k] = fmaf(f.z, nk, acc[2][k]);
                acc[3][k] = fmaf(f.w, nk, acc[3][k]);
            }
        }

        // block-level combine via LDS (pad 17 breaks stride-16 banks)
        __shared__ float lds[256][17];
        #pragma unroll
        for (int i = 0; i < 4; ++i) {
            lds[tid][i * 4 + 0] = acc[i][0];
            lds[tid][i * 4 + 1] = acc[i][1];
            lds[tid][i * 4 + 2] = acc[i][2];
            lds[tid][i * 4 + 3] = acc[i][3];
        }
        __syncthreads();

        // remap to ws slot contract: tid = (u = tid>>2, j = tid&3);
        // j==0 -> S (lds k=3), j=1..3 -> M[j-1] (lds k=j-1).
        const int u    = tid >> 2;
        const int j    = tid & 3;
        const int ug   = u >> 2;
        const int sub  = u & 3;
        const int slot = (j == 0) ? (sub * 4 + 3) : (sub * 4 + (j - 1));
        float s = 0.f;
        #pragma unroll
        for (int src = 0; src < 16; ++src) {
            const int t = (src & 3) * 64 + (src >> 2) * 16 + ug;
            s += lds[t][slot];
        }

        // publish via RMW (global_atomic_swap -> device coherence point),
        // ack-wait (uncontended, one round trip), then RMW flag.
        (void)__hip_atomic_exchange(&ws[(size_t)blk * 256 + tid], s,
                                    __ATOMIC_RELAXED, __HIP_MEMORY_SCOPE_AGENT);
        asm volatile("s_waitcnt vmcnt(0)" ::: "memory");
        __syncthreads();
        if (tid == 0)
            (void)__hip_atomic_exchange(&flags[blk], SENT,
                                        __ATOMIC_RELAXED, __HIP_MEMORY_SCOPE_AGENT);
        return;
    }

    // ---------------- finalizer: one block per batch ----------------
    const int b = blk - NPROD;

    if (tid < BLOCKS_PER_B) {
        while (__hip_atomic_load(&flags[b * BLOCKS_PER_B + tid],
                                 __ATOMIC_RELAXED,
                                 __HIP_MEMORY_SCOPE_AGENT) != SENT)
            __builtin_amdgcn_s_sleep(1);
    }
    __syncthreads();
    // reset flags for the next replay (RMW; partials independent of flags)
    if (tid < BLOCKS_PER_B)
        (void)__hip_atomic_exchange(&flags[b * BLOCKS_PER_B + tid], 0u,
                                    __ATOMIC_RELAXED, __HIP_MEMORY_SCOPE_AGENT);

    // cross-chunk combine: slot tid over 32 chunks, atomic loads (coherence
    // point; coalesced 256-float rows per chunk).
    float s = 0.f;
    {
        const float* base = ws + (size_t)b * BLOCKS_PER_B * 256;
        #pragma unroll
        for (int c = 0; c < BLOCKS_PER_B; ++c)
            s += __hip_atomic_load(&base[(size_t)c * 256 + tid],
                                   __ATOMIC_RELAXED, __HIP_MEMORY_SCOPE_AGENT);
    }
    __shared__ float sm[256];
    sm[tid] = s;                      // sm[u*4 + j]: j==0 S, j=1..3 M[j-1]
    __syncthreads();

    // tiny matmul: 512 outputs over 256 threads = 2 each; sole writer.
    // FIX vs R14/R15: read via the ws slot contract (S at +0, M[k] at +1+k).
    const float scaleS = 0.125f / (float)N_;                       // PATH_COEFF / N
    const float scaleV = 0.125f * 1.7320508075688772f / (float)N_; // PATH_COEFF*sqrt(3)/N

    #pragma unroll
    for (int half = 0; half < 2; ++half) {
        const int o = tid + half * 256;
        float acc = 0.f;
        if (o < 128) {
            #pragma unroll
            for (int u = 0; u < 64; ++u) acc += sm[u * 4 + 0] * W0[u * 128 + o];
            out[b * 512 + o] = acc * scaleS;
        } else {
            const int idx = o - 128;       // 0..383
            const int w = idx / 3;
            const int k = idx - 3 * w;
            #pragma unroll
            for (int u = 0; u < 64; ++u) acc += sm[u * 4 + 1 + k] * W1[u * 128 + w];
            out[b * 512 + 128 + idx] = acc * scaleV;
        }
    }
}

extern "C" void kernel_launch(void* const* d_in, const int* in_sizes, int n_in,
                              void* d_out, int out_size, void* d_ws, size_t ws_size,
                              hipStream_t stream) {
    const float* feat = (const float*)d_in[0];
    const float* pos  = (const float*)d_in[1];
    const float* W0   = (const float*)d_in[2];
    const float* W1   = (const float*)d_in[3];
    float* out = (float*)d_out;
    float* ws  = (float*)d_ws;   // needs NPROD*256*4 + NPROD*4 = 514 KiB

    so3_single_kernel<<<GRID_, 256, 0, stream>>>(feat, pos, W0, W1, out, ws);
}

// Round 17
// 12.552 us; speedup vs baseline: 1.0604x; 1.0092x over previous
//
#include <hip/hip_runtime.h>

// Problem constants (match reference)
#define B_ 16
#define N_ 8192
#define U_ 64        // INPUT_DIM
#define W_ 128       // LATENT_DIM
#define BLOCKS_PER_B 32
#define ROWS_PER_BLOCK (N_ / BLOCKS_PER_B)   // 256 = blockDim
#define NPROD (B_ * BLOCKS_PER_B)            // 512 producer blocks (2/CU)
#define NFIN  B_                             // 16 finalizer blocks (one per batch)
#define GRID_ (NPROD + NFIN)                 // 528
#define SENT 0x5AC3F00Du

typedef float f32x4 __attribute__((ext_vector_type(4)));

// Single-node producer/consumer (R16 structure, 12.67 us).
// This round's single variable: feat prefetch issued BEFORE the pos
// prologue, so the 64 KB/block feat stream drains underneath the pos load
// latency + normalize + barrier instead of after it. No arithmetic change
// anywhere -> absmax must stay bit-identical.
// Ledger: R4 grid-sync +107us; R7 threadfence +50us; R8 contended-RMW wait
// +14us; R14/R15 fails were a finalizer indexing bug (not coherence).
// ws: [NPROD][256] partials (512 KiB) + NPROD u32 flags (2 KiB).
// ws slot contract: slot = u*4 + j; j==0 -> S, j=1..3 -> M[j-1].
// out layout: [B,512]: o<128 scalar path, 128+3w+k vector path.

__global__ __launch_bounds__(256, 2) void so3_single_kernel(
    const float* __restrict__ feat,   // [B,N,64]
    const float* __restrict__ pos,    // [B,N,3]
    const float* __restrict__ W0,     // [64,128]
    const float* __restrict__ W1,     // [64,128]
    float* __restrict__ out,          // [B,512]
    float* __restrict__ ws)
{
    const int blk = blockIdx.x;
    const int tid = threadIdx.x;      // 0..255 (4 waves)
    unsigned* flags = (unsigned*)(ws + (size_t)NPROD * 256);

    if (blk < NPROD) {
        // ---------------- producer ----------------
        const int b     = blk / BLOCKS_PER_B;
        const int chunk = blk % BLOCKS_PER_B;
        const int row0  = chunk * ROWS_PER_BLOCK;
        const int grp   = tid & 15;            // feature group: feats 4*grp..4*grp+3
        const int rsub  = tid >> 4;            // 0..15: row within a 16-row group

        const f32x4* fbase = (const f32x4*)(feat + (size_t)b * N_ * U_);

        // (1) issue all 16 feat loads FIRST -- in flight during the prologue.
        f32x4 fb[16];
        #pragma unroll
        for (int it = 0; it < 16; ++it) {
            const int nl = it * 16 + rsub;
            fb[it] = __builtin_nontemporal_load(
                &fbase[(size_t)(row0 + nl) * 16 + grp]);
        }

        // (2) pos prologue: normalize once per row into LDS.
        __shared__ f32x4 nlds[ROWS_PER_BLOCK]; // 4 KiB
        {
            const float* p = pos + ((size_t)b * N_ + row0 + tid) * 3;
            const float px = p[0], py = p[1], pz = p[2];   // coalesced 3 KiB
            const float inv = rsqrtf(px * px + py * py + pz * pz);
            f32x4 v;
            v.x = px * inv; v.y = py * inv; v.z = pz * inv; v.w = 1.0f;
            nlds[tid] = v;
        }
        __syncthreads();

        // (3) FMA loop. acc[i][k]: i = feat sub-index, k=0..2 -> M[k], k=3 -> S.
        float acc[4][4] = {{0.f,0.f,0.f,0.f},{0.f,0.f,0.f,0.f},
                           {0.f,0.f,0.f,0.f},{0.f,0.f,0.f,0.f}};

        #pragma unroll
        for (int it = 0; it < 16; ++it) {
            const int nl = it * 16 + rsub;
            const f32x4 f  = fb[it];
            const f32x4 nv = nlds[nl];         // ds_read_b128, 16-way broadcast
            #pragma unroll
            for (int k = 0; k < 4; ++k) {
                const float nk = (k == 0) ? nv.x : (k == 1) ? nv.y
                               : (k == 2) ? nv.z : nv.w;   // nv.w==1.0 -> sum
                acc[0][k] = fmaf(f.x, nk, acc[0][k]);
                acc[1][k] = fmaf(f.y, nk, acc[1][k]);
                acc[2][k] = fmaf(f.z, nk, acc[2][k]);
                acc[3][k] = fmaf(f.w, nk, acc[3][k]);
            }
        }

        // (4) block-level combine via LDS (pad 17 breaks stride-16 banks).
        __shared__ float lds[256][17];
        #pragma unroll
        for (int i = 0; i < 4; ++i) {
            lds[tid][i * 4 + 0] = acc[i][0];
            lds[tid][i * 4 + 1] = acc[i][1];
            lds[tid][i * 4 + 2] = acc[i][2];
            lds[tid][i * 4 + 3] = acc[i][3];
        }
        __syncthreads();

        // remap to ws slot contract: tid = (u = tid>>2, j = tid&3);
        // j==0 -> S (lds k=3), j=1..3 -> M[j-1] (lds k=j-1).
        const int u    = tid >> 2;
        const int j    = tid & 3;
        const int ug   = u >> 2;
        const int sub  = u & 3;
        const int slot = (j == 0) ? (sub * 4 + 3) : (sub * 4 + (j - 1));
        float s = 0.f;
        #pragma unroll
        for (int src = 0; src < 16; ++src) {
            const int t = (src & 3) * 64 + (src >> 2) * 16 + ug;
            s += lds[t][slot];
        }

        // (5) publish via RMW (coherence point), ack-wait, flag.
        (void)__hip_atomic_exchange(&ws[(size_t)blk * 256 + tid], s,
                                    __ATOMIC_RELAXED, __HIP_MEMORY_SCOPE_AGENT);
        asm volatile("s_waitcnt vmcnt(0)" ::: "memory");
        __syncthreads();
        if (tid == 0)
            (void)__hip_atomic_exchange(&flags[blk], SENT,
                                        __ATOMIC_RELAXED, __HIP_MEMORY_SCOPE_AGENT);
        return;
    }

    // ---------------- finalizer: one block per batch ----------------
    const int b = blk - NPROD;

    if (tid < BLOCKS_PER_B) {
        while (__hip_atomic_load(&flags[b * BLOCKS_PER_B + tid],
                                 __ATOMIC_RELAXED,
                                 __HIP_MEMORY_SCOPE_AGENT) != SENT)
            __builtin_amdgcn_s_sleep(1);
    }
    __syncthreads();
    // reset flags for the next replay
    if (tid < BLOCKS_PER_B)
        (void)__hip_atomic_exchange(&flags[b * BLOCKS_PER_B + tid], 0u,
                                    __ATOMIC_RELAXED, __HIP_MEMORY_SCOPE_AGENT);

    // cross-chunk combine: slot tid over 32 chunks (atomic loads, coherence
    // point; coalesced 256-float rows per chunk).
    float s = 0.f;
    {
        const float* base = ws + (size_t)b * BLOCKS_PER_B * 256;
        #pragma unroll
        for (int c = 0; c < BLOCKS_PER_B; ++c)
            s += __hip_atomic_load(&base[(size_t)c * 256 + tid],
                                   __ATOMIC_RELAXED, __HIP_MEMORY_SCOPE_AGENT);
    }
    __shared__ float sm[256];
    sm[tid] = s;                      // sm[u*4 + j]: j==0 S, j=1..3 M[j-1]
    __syncthreads();

    // tiny matmul per ws slot contract (S at +0, M[k] at +1+k); sole writer.
    const float scaleS = 0.125f / (float)N_;                       // PATH_COEFF / N
    const float scaleV = 0.125f * 1.7320508075688772f / (float)N_; // PATH_COEFF*sqrt(3)/N

    #pragma unroll
    for (int half = 0; half < 2; ++half) {
        const int o = tid + half * 256;
        float acc = 0.f;
        if (o < 128) {
            #pragma unroll
            for (int u = 0; u < 64; ++u) acc += sm[u * 4 + 0] * W0[u * 128 + o];
            out[b * 512 + o] = acc * scaleS;
        } else {
            const int idx = o - 128;       // 0..383
            const int w = idx / 3;
            const int k = idx - 3 * w;
            #pragma unroll
            for (int u = 0; u < 64; ++u) acc += sm[u * 4 + 1 + k] * W1[u * 128 + w];
            out[b * 512 + 128 + idx] = acc * scaleV;
        }
    }
}

extern "C" void kernel_launch(void* const* d_in, const int* in_sizes, int n_in,
                              void* d_out, int out_size, void* d_ws, size_t ws_size,
                              hipStream_t stream) {
    const float* feat = (const float*)d_in[0];
    const float* pos  = (const float*)d_in[1];
    const float* W0   = (const float*)d_in[2];
    const float* W1   = (const float*)d_in[3];
    float* out = (float*)d_out;
    float* ws  = (float*)d_ws;   // needs NPROD*256*4 + NPROD*4 = 514 KiB

    so3_single_kernel<<<GRID_, 256, 0, stream>>>(feat, pos, W0, W1, out, ws);
}